// Round 3
// baseline (17990.109 us; speedup 1.0000x reference)
//
#include <hip/hip_runtime.h>
#include <hip/hip_cooperative_groups.h>
#include <math.h>

namespace cg = cooperative_groups;

#define BSZ 32
#define TT  32
#define XD  128
#define HD  512
#define VT  2048
#define ET  463
#define GKS 8
#define VKS 8
#define NBLK 256
#define NTHR 512

__device__ __forceinline__ float sigf(float x){ return 1.f/(1.f+expf(-x)); }
__device__ __forceinline__ float logsigf(float x){
    return (x >= 0.f) ? -log1pf(expf(-x)) : x - log1pf(expf(x));
}

// ---- 512-thread block reductions (8 waves; red must be 8 floats) -------------------
__device__ __forceinline__ float bsum512(float v, float* red, int tid){
    #pragma unroll
    for (int off = 32; off > 0; off >>= 1) v += __shfl_xor(v, off);
    if ((tid & 63) == 0) red[tid >> 6] = v;
    __syncthreads();
    float r = red[0]+red[1]+red[2]+red[3]+red[4]+red[5]+red[6]+red[7];
    __syncthreads();
    return r;
}
__device__ __forceinline__ float bmax512(float v, float* red, int tid){
    #pragma unroll
    for (int off = 32; off > 0; off >>= 1) v = fmaxf(v, __shfl_xor(v, off));
    if ((tid & 63) == 0) red[tid >> 6] = v;
    __syncthreads();
    float r = fmaxf(fmaxf(fmaxf(red[0],red[1]),fmaxf(red[2],red[3])),
                    fmaxf(fmaxf(red[4],red[5]),fmaxf(red[6],red[7])));
    __syncthreads();
    return r;
}

// ---------------- LSTM pre-activation GEMM phase (256 blocks, 512 thr) ---------------
// unit: jc = bid&15, d = (bid>>4)&1, ks = bid>>5. thread: 2 j x 4 b accumulators.
__device__ __forceinline__ void gemm_phase(
    const float* __restrict__ srcA, int KA, const float* __restrict__ srcB, int KB,
    const float* __restrict__ hbase, const float* __restrict__ Wih,
    const float* __restrict__ Whh, float* __restrict__ gpart,
    int bid, int tid, float* tile)
{
    const int jc = bid & 15, d = (bid >> 4) & 1, ks = bid >> 5;
    const int jg = tid & 63, bg = tid >> 6;
    const int j0 = jc*128 + jg*2;
    const int b0 = bg*4;
    const int K1 = KA + KB;
    const int cA = KA >> 6, cin = K1 >> 6;
    const int nct = cin + 8;
    const int per = (nct + GKS - 1) / GKS;
    int c0 = ks*per, c1 = min(nct, c0+per);
    float acc[2][4] = {{0.f,0.f,0.f,0.f},{0.f,0.f,0.f,0.f}};
    for (int c = c0; c < c1; ++c){
        const float* src; int stride, kb, wcol; const float* Wb; int Kw;
        if (c < cA){ src = srcA; stride = KA; kb = c*64; wcol = c*64;
                     Wb = Wih + (size_t)d*2048*K1; Kw = K1; }
        else if (c < cin){ src = srcB; stride = KB; kb = (c-cA)*64; wcol = c*64;
                           Wb = Wih + (size_t)d*2048*K1; Kw = K1; }
        else { src = hbase + d*(BSZ*HD); stride = HD; kb = (c-cin)*64; wcol = kb;
               Wb = Whh + (size_t)d*2048*512; Kw = 512; }
        #pragma unroll
        for (int i = 0; i < 4; ++i){
            int idx = i*512 + tid; int kk = idx & 63, b = idx >> 6;
            tile[kk*36 + b] = src[b*stride + kb + kk];
        }
        __syncthreads();
        const float* w0p = Wb + (size_t)(j0+0)*Kw + wcol;
        const float* w1p = Wb + (size_t)(j0+1)*Kw + wcol;
        #pragma unroll
        for (int kk = 0; kk < 64; kk += 4){
            float4 a0 = *(const float4*)&tile[(kk+0)*36 + b0];
            float4 a1 = *(const float4*)&tile[(kk+1)*36 + b0];
            float4 a2 = *(const float4*)&tile[(kk+2)*36 + b0];
            float4 a3 = *(const float4*)&tile[(kk+3)*36 + b0];
            float4 w0 = *(const float4*)(w0p + kk);
            acc[0][0] += a0.x*w0.x + a1.x*w0.y + a2.x*w0.z + a3.x*w0.w;
            acc[0][1] += a0.y*w0.x + a1.y*w0.y + a2.y*w0.z + a3.y*w0.w;
            acc[0][2] += a0.z*w0.x + a1.z*w0.y + a2.z*w0.z + a3.z*w0.w;
            acc[0][3] += a0.w*w0.x + a1.w*w0.y + a2.w*w0.z + a3.w*w0.w;
            float4 w1 = *(const float4*)(w1p + kk);
            acc[1][0] += a0.x*w1.x + a1.x*w1.y + a2.x*w1.z + a3.x*w1.w;
            acc[1][1] += a0.y*w1.x + a1.y*w1.y + a2.y*w1.z + a3.y*w1.w;
            acc[1][2] += a0.z*w1.x + a1.z*w1.y + a2.z*w1.z + a3.z*w1.w;
            acc[1][3] += a0.w*w1.x + a1.w*w1.y + a2.w*w1.z + a3.w*w1.w;
        }
        __syncthreads();
    }
    #pragma unroll
    for (int jj = 0; jj < 2; ++jj){
        #pragma unroll
        for (int bb = 0; bb < 4; ++bb)
            gpart[((size_t)(d*GKS + ks)*BSZ + (b0+bb))*2048 + (j0+jj)] = acc[jj][bb];
    }
}

// ---------------- LSTM gates phase (blocks 0-63) -------------------------------------
__device__ __forceinline__ void gates_phase(const float* __restrict__ gpart,
    const float* __restrict__ bih, const float* __restrict__ bhh,
    float* __restrict__ cstate, float* __restrict__ hstate,
    float* __restrict__ flat, float* __restrict__ lout, int l, int bid, int tid)
{
    int idx = bid*NTHR + tid;
    if (idx >= 2*BSZ*HD) return;
    int u = idx & 511, b = (idx >> 9) & 31, d = idx >> 14;
    int cell = 2*l + d;
    float g[4];
    #pragma unroll
    for (int xg = 0; xg < 4; ++xg){
        int j = xg*512 + u;
        float s = bih[d*2048 + j] + bhh[d*2048 + j];
        #pragma unroll
        for (int ks = 0; ks < GKS; ++ks)
            s += gpart[((size_t)(d*GKS + ks)*BSZ + b)*2048 + j];
        g[xg] = s;
    }
    float ig = sigf(g[0]), fg = sigf(g[1]), og = sigf(g[3]);
    float gg = tanhf(g[2]);
    int ci = (cell*BSZ + b)*HD + u;
    float c2 = fg*cstate[ci] + ig*gg;
    cstate[ci] = c2;
    float h = og*tanhf(c2);
    hstate[ci] = h;
    flat[b*2048 + cell*HD + u] = h;
    if (lout) lout[b*1024 + d*HD + u] = h;
}

// ---------------- combined GEMV phase (blocks 0-159) ---------------------------------
// unit: ksi = bid&7 (k0=ksi*256), u = bid>>3: u<16 -> Wy, else WE.
__device__ __forceinline__ void gemv_phase(const float* __restrict__ fin,
    const float* __restrict__ Wy, const float* __restrict__ WE,
    float* __restrict__ vtp, float* __restrict__ ep, int bid, int tid, float* tile)
{
    if (bid >= 160) return;
    const int ksi = bid & 7, u = bid >> 3;
    const float* Wm; float* outp; int Mdim, mb;
    if (u < 16){ Wm = Wy; outp = vtp; Mdim = VT; mb = u; }
    else       { Wm = WE; outp = ep;  Mdim = ET; mb = u - 16; }
    const int lane = tid & 63, bg = tid >> 6;
    const int b0 = bg*4;
    const int m0 = mb*128 + lane, m1 = m0 + 64;
    const int k0 = ksi*256;
    #pragma unroll
    for (int i = 0; i < 16; ++i){
        int idx = i*512 + tid; int kk = idx & 255, b = idx >> 8;
        tile[kk*36 + b] = fin[b*2048 + k0 + kk];
    }
    __syncthreads();
    bool v0 = m0 < Mdim, v1 = m1 < Mdim;
    float acc[8] = {0.f,0.f,0.f,0.f,0.f,0.f,0.f,0.f};
    for (int kk = 0; kk < 256; ++kk){
        float4 a = *(const float4*)&tile[kk*36 + b0];
        const float* wr = Wm + (size_t)(k0+kk)*Mdim;
        float w0 = v0 ? wr[m0] : 0.f;
        float w1 = v1 ? wr[m1] : 0.f;
        acc[0]+=a.x*w0; acc[1]+=a.y*w0; acc[2]+=a.z*w0; acc[3]+=a.w*w0;
        acc[4]+=a.x*w1; acc[5]+=a.y*w1; acc[6]+=a.z*w1; acc[7]+=a.w*w1;
    }
    if (v0){
        #pragma unroll
        for (int bb = 0; bb < 4; ++bb)
            outp[((size_t)ksi*BSZ + b0+bb)*Mdim + m0] = acc[bb];
    }
    if (v1){
        #pragma unroll
        for (int bb = 0; bb < 4; ++bb)
            outp[((size_t)ksi*BSZ + b0+bb)*Mdim + m1] = acc[4+bb];
    }
}

// ---------------- layernorm phase (blocks 0-31) --------------------------------------
__device__ __forceinline__ void ln_phase(const float* __restrict__ ep,
    float* __restrict__ iv, int bid, int tid, float* red)
{
    if (bid >= 32) return;
    const int b = bid;
    float myv = 0.f;
    if (tid < ET){
        #pragma unroll
        for (int s = 0; s < VKS; ++s) myv += ep[((size_t)s*BSZ + b)*ET + tid];
    }
    float mean = bsum512(myv, red, tid) * (1.f/ET);
    float dd = (tid < ET) ? (myv - mean) : 0.f;
    float var = bsum512(dd*dd, red, tid) * (1.f/ET);
    float rinv = 1.f / sqrtf(var + 1e-5f);
    if (tid < ET) iv[b*ET + tid] = (myv - mean)*rinv;
}

// ---------------- sort (blocks 0-31) || cw_score (blocks 32-95) ----------------------
__device__ __forceinline__ void sortcw_phase(
    const float* __restrict__ iv, const float* __restrict__ lrw,
    const float* __restrict__ lww, float* __restrict__ ubuf,
    float* __restrict__ allocw, const float* __restrict__ M,
    float* __restrict__ scw, int bid, int tid, int lane, int wid,
    float* smf, float* saux)
{
    if (bid < 32){
        const int b = bid;
        float f0 = sigf(iv[b*ET + 453]);
        float f1 = sigf(iv[b*ET + 454]);
        float f2 = sigf(iv[b*ET + 455]);
        float f3 = sigf(iv[b*ET + 456]);
        float un2[2];
        #pragma unroll
        for (int e = 0; e < 2; ++e){
            int i = tid + e*512;
            float4 lw4 = *(const float4*)&lrw[((size_t)(b*1024 + i))*4];
            float ret = (1.f-f0*lw4.x)*(1.f-f1*lw4.y)*(1.f-f2*lw4.z)*(1.f-f3*lw4.w);
            float uo = ubuf[b*1024 + i], lwo = lww[b*1024 + i];
            float un = (uo + lwo - uo*lwo)*ret;
            ubuf[b*1024 + i] = un;
            un2[e] = un;
        }
        // stable bitonic sort of 1024 (value<<32|idx); thread owns indices tid, tid+512
        unsigned long long kA = ((unsigned long long)__float_as_uint(un2[0]) << 32) | (unsigned)tid;
        unsigned long long kB = ((unsigned long long)__float_as_uint(un2[1]) << 32) | (unsigned)(tid + 512);
        unsigned long long* keys = (unsigned long long*)smf;
        for (int k = 2; k <= 1024; k <<= 1){
            for (int j = k >> 1; j > 0; j >>= 1){
                if (j >= 512){
                    unsigned long long lo = kA < kB ? kA : kB;
                    unsigned long long hi = kA < kB ? kB : kA;
                    kA = lo; kB = hi;          // k=1024: ascending merge
                } else if (j >= 64){
                    keys[tid] = kA; keys[tid + 512] = kB;
                    __syncthreads();
                    unsigned long long oA = keys[tid ^ j];
                    unsigned long long oB = keys[(tid + 512) ^ j];
                    __syncthreads();
                    bool upA = ((tid & k) == 0);
                    bool upB = (((tid + 512) & k) == 0);
                    bool mA = (((tid & j) == 0) == upA);
                    bool mB = ((((tid + 512) & j) == 0) == upB);
                    kA = mA ? (kA < oA ? kA : oA) : (kA > oA ? kA : oA);
                    kB = mB ? (kB < oB ? kB : oB) : (kB > oB ? kB : oB);
                } else {
                    unsigned long long oA = __shfl_xor(kA, j);
                    unsigned long long oB = __shfl_xor(kB, j);
                    bool upA = ((tid & k) == 0);
                    bool upB = (((tid + 512) & k) == 0);
                    bool mA = (((tid & j) == 0) == upA);
                    bool mB = ((((tid + 512) & j) == 0) == upB);
                    kA = mA ? (kA < oA ? kA : oA) : (kA > oA ? kA : oA);
                    kB = mB ? (kB < oB ? kB : oB) : (kB > oB ? kB : oB);
                }
            }
        }
        float suA = __uint_as_float((unsigned)(kA >> 32));
        float suB = __uint_as_float((unsigned)(kB >> 32));
        int idxA = (int)(kA & 0xffffffffu);
        int idxB = (int)(kB & 0xffffffffu);
        // exclusive cumprod over sorted order (positions tid and tid+512)
        float pA = suA, pB = suB;
        #pragma unroll
        for (int o = 1; o < 64; o <<= 1){
            float qa = __shfl_up(pA, o); if (lane >= o) pA *= qa;
            float qb = __shfl_up(pB, o); if (lane >= o) pB *= qb;
        }
        if (lane == 63){ saux[wid] = pA; saux[8 + wid] = pB; }
        __syncthreads();
        if (tid == 0){
            float r = 1.f;
            #pragma unroll
            for (int i = 0; i < 8; ++i){ saux[16+i] = r; r *= saux[i]; }
            #pragma unroll
            for (int i = 0; i < 8; ++i){ saux[24+i] = r; r *= saux[8+i]; }
        }
        __syncthreads();
        float eA = __shfl_up(pA, 1); if (lane == 0) eA = 1.f;
        float eB = __shfl_up(pB, 1); if (lane == 0) eB = 1.f;
        allocw[b*1024 + idxA] = (1.f - suA) * (eA * saux[16 + wid]);
        allocw[b*1024 + idxB] = (1.f - suB) * (eB * saux[24 + wid]);
    } else if (bid < 96){
        const int u = bid - 32;
        const int b = u >> 1;
        const int n = (u & 1)*512 + tid;
        float* key = saux;
        if (tid < 64) key[tid] = iv[b*ET + 260 + tid];
        __syncthreads();
        float ksq = 0.f;
        #pragma unroll
        for (int w = 0; w < 64; ++w) ksq += key[w]*key[w];
        float kden = sqrtf(ksq) + 1e-8f;
        float wb = 1.f - logsigf(iv[b*ET + 324]);
        const float* Mrow = M + ((size_t)b*1024 + n)*64;
        float dot = 0.f, msq = 0.f;
        #pragma unroll
        for (int w = 0; w < 64; w += 4){
            float4 mv = *(const float4*)(Mrow + w);
            dot += mv.x*key[w] + mv.y*key[w+1] + mv.z*key[w+2] + mv.w*key[w+3];
            msq += mv.x*mv.x + mv.y*mv.y + mv.z*mv.z + mv.w*mv.w;
        }
        scw[b*1024 + n] = wb*dot/((sqrtf(msq) + 1e-8f)*kden);
    }
}

// ---------------- memup phase (blocks 0-63): cw softmax+ww fused, M update, scr ------
__device__ __forceinline__ void memup_phase(float* __restrict__ M,
    const float* __restrict__ scw, const float* __restrict__ allocw,
    const float* __restrict__ iv, float* __restrict__ lww, float* __restrict__ scr,
    int bid, int tid, float* red, float* aux)
{
    if (bid >= 64) return;
    const int b = bid >> 1, half = bid & 1;
    const int n = half*512 + tid;
    // content-write softmax over all 1024 n (redundant per half-block, cheap)
    float s0 = scw[b*1024 + tid], s1 = scw[b*1024 + 512 + tid];
    float mx = bmax512(fmaxf(s0, s1), red, tid);
    float tot = bsum512(expf(s0-mx) + expf(s1-mx), red, tid);
    float own = half ? s1 : s0;
    float cwv = expf(own - mx)/tot;
    float ag = sigf(iv[b*ET + 457]), wg = sigf(iv[b*ET + 458]);
    float wwv = wg*(ag*allocw[b*1024 + n] + (1.f-ag)*cwv);
    lww[b*1024 + n] = wwv;
    // stage erase [0..63], wvec [64..127], rkn [128..383], nrm [384..387], rb [388..391]
    if (tid < 64){ aux[tid] = sigf(iv[b*ET + 325 + tid]); aux[64+tid] = iv[b*ET + 389 + tid]; }
    if (tid >= 64 && tid < 320) aux[64 + tid] = iv[b*ET + (tid - 64)];
    __syncthreads();
    if (tid < 4){
        float s = 0.f;
        #pragma unroll
        for (int w = 0; w < 64; ++w){ float v = aux[128 + w*4 + tid]; s += v*v; }
        aux[384 + tid] = sqrtf(s) + 1e-8f;
        aux[388 + tid] = 1.f - logsigf(iv[b*ET + 256 + tid]);
    }
    __syncthreads();
    if (tid < 256) aux[128 + tid] = aux[128 + tid] / aux[384 + (tid & 3)];
    __syncthreads();
    float* Mrow = M + ((size_t)b*1024 + n)*64;
    float dr0=0.f, dr1=0.f, dr2=0.f, dr3=0.f, msq2=0.f;
    #pragma unroll
    for (int w = 0; w < 64; w += 4){
        float4 mv = *(const float4*)(Mrow + w);
        mv.x = mv.x*(1.f - wwv*aux[w+0]) + wwv*aux[64+w+0];
        mv.y = mv.y*(1.f - wwv*aux[w+1]) + wwv*aux[64+w+1];
        mv.z = mv.z*(1.f - wwv*aux[w+2]) + wwv*aux[64+w+2];
        mv.w = mv.w*(1.f - wwv*aux[w+3]) + wwv*aux[64+w+3];
        *(float4*)(Mrow + w) = mv;
        msq2 += mv.x*mv.x + mv.y*mv.y + mv.z*mv.z + mv.w*mv.w;
        dr0 += mv.x*aux[128+(w+0)*4+0] + mv.y*aux[128+(w+1)*4+0] + mv.z*aux[128+(w+2)*4+0] + mv.w*aux[128+(w+3)*4+0];
        dr1 += mv.x*aux[128+(w+0)*4+1] + mv.y*aux[128+(w+1)*4+1] + mv.z*aux[128+(w+2)*4+1] + mv.w*aux[128+(w+3)*4+1];
        dr2 += mv.x*aux[128+(w+0)*4+2] + mv.y*aux[128+(w+1)*4+2] + mv.z*aux[128+(w+2)*4+2] + mv.w*aux[128+(w+3)*4+2];
        dr3 += mv.x*aux[128+(w+0)*4+3] + mv.y*aux[128+(w+1)*4+3] + mv.z*aux[128+(w+2)*4+3] + mv.w*aux[128+(w+3)*4+3];
    }
    float den = sqrtf(msq2) + 1e-8f;
    scr[((size_t)(b*4 + 0))*1024 + n] = aux[388]*dr0/den;
    scr[((size_t)(b*4 + 1))*1024 + n] = aux[389]*dr1/den;
    scr[((size_t)(b*4 + 2))*1024 + n] = aux[390]*dr2/den;
    scr[((size_t)(b*4 + 3))*1024 + n] = aux[391]*dr3/den;
}

// ---------------- rv phase (blocks 0-63): read softmax fused, writes lrw + rvp -------
__device__ __forceinline__ void rv_phase(const float* __restrict__ M,
    const float* __restrict__ scr, float* __restrict__ lrw, float* __restrict__ rvp,
    int bid, int tid, int lane, int wid, float* red, float* aux, float* rwS)
{
    if (bid >= 64) return;
    const int b = bid >> 1, half = bid & 1;
    // softmax denominators per r over all 1024 n: r_ = tid>>7, 8 n per thread
    const int r_ = tid >> 7;
    const int i8 = tid & 127;
    const float* srow = scr + ((size_t)(b*4 + r_))*1024;
    float vloc[8];
    float lm = -1e30f;
    #pragma unroll
    for (int i = 0; i < 8; ++i){ vloc[i] = srow[i8*8 + i]; lm = fmaxf(lm, vloc[i]); }
    #pragma unroll
    for (int off = 32; off > 0; off >>= 1) lm = fmaxf(lm, __shfl_xor(lm, off));
    if (lane == 0) red[wid] = lm;
    __syncthreads();
    if (tid < 4) aux[tid] = fmaxf(red[2*tid], red[2*tid+1]);
    __syncthreads();
    float mxr = aux[r_];
    float lsum = 0.f;
    #pragma unroll
    for (int i = 0; i < 8; ++i) lsum += expf(vloc[i] - mxr);
    #pragma unroll
    for (int off = 32; off > 0; off >>= 1) lsum += __shfl_xor(lsum, off);
    if (lane == 0) red[wid] = lsum;
    __syncthreads();
    if (tid < 4) aux[4+tid] = red[2*tid] + red[2*tid+1];
    __syncthreads();
    // rw for own half (512 n x 4 r): stage LDS + write global lrw
    #pragma unroll
    for (int i = 0; i < 4; ++i){
        int idx = i*512 + tid;
        int j = idx >> 2, r = idx & 3;
        int n = half*512 + j;
        float v = expf(scr[((size_t)(b*4 + r))*1024 + n] - aux[r]) / aux[4+r];
        rwS[j*4 + r] = v;
        lrw[((size_t)(b*1024 + n))*4 + r] = v;
    }
    __syncthreads();
    // rv partials over own half's two n-quarters
    const int q = tid >> 8;
    const int r = (tid >> 6) & 3, w = tid & 63;
    const int ns = half*2 + q;
    const float* Mb = M + ((size_t)b*1024 + ns*256)*64;
    const float* rb = rwS + (q*256)*4 + r;
    float acc = 0.f;
    for (int i = 0; i < 256; ++i)
        acc += Mb[(size_t)i*64 + w] * rb[i*4];
    rvp[((size_t)(ns*BSZ + b))*256 + r*64 + w] = acc;
}

// ---------------- yfin phase (blocks 0-7): lrv, yt = rv@Wr + vtp, out = max ----------
__device__ __forceinline__ void yfin_phase(const float* __restrict__ rvp,
    const float* __restrict__ Wr, const float* __restrict__ vtp,
    float* __restrict__ lrv, float* __restrict__ out, int t, int bid, int tid, float* lt)
{
    if (bid >= 8) return;
    const int mg = tid & 63, bg = tid >> 6;
    const int m0 = bid*256 + mg*4;
    const int b0 = bg*4;
    #pragma unroll
    for (int i = 0; i < 16; ++i){
        int idx = i*512 + tid; int k = idx & 255, b = idx >> 8;
        int w = k >> 2, r = k & 3;
        int ksrc = r*64 + w;
        float s = 0.f;
        #pragma unroll
        for (int c = 0; c < 4; ++c) s += rvp[((size_t)(c*BSZ + b))*256 + ksrc];
        lt[k*36 + b] = s;
        if (bid == 0) lrv[b*256 + k] = s;
    }
    __syncthreads();
    float acc[4][4] = {{0.f}};
    for (int kk = 0; kk < 256; ++kk){
        float4 av = *(const float4*)&lt[kk*36 + b0];
        float4 wv = *(const float4*)&Wr[(size_t)kk*VT + m0];
        acc[0][0]+=av.x*wv.x; acc[0][1]+=av.x*wv.y; acc[0][2]+=av.x*wv.z; acc[0][3]+=av.x*wv.w;
        acc[1][0]+=av.y*wv.x; acc[1][1]+=av.y*wv.y; acc[1][2]+=av.y*wv.z; acc[1][3]+=av.y*wv.w;
        acc[2][0]+=av.z*wv.x; acc[2][1]+=av.z*wv.y; acc[2][2]+=av.z*wv.z; acc[2][3]+=av.z*wv.w;
        acc[3][0]+=av.w*wv.x; acc[3][1]+=av.w*wv.y; acc[3][2]+=av.w*wv.z; acc[3][3]+=av.w*wv.w;
    }
    #pragma unroll
    for (int bi = 0; bi < 4; ++bi){
        int b = b0 + bi;
        float4 s = make_float4(acc[bi][0], acc[bi][1], acc[bi][2], acc[bi][3]);
        #pragma unroll
        for (int sp = 0; sp < VKS; ++sp){
            float4 vp = *(const float4*)&vtp[((size_t)sp*BSZ + b)*VT + m0];
            s.x += vp.x; s.y += vp.y; s.z += vp.z; s.w += vp.w;
        }
        float4* op = (float4*)&out[(size_t)b*VT + m0];
        if (t == 0){ *op = s; }
        else {
            float4 cur = *op;
            cur.x = fmaxf(cur.x, s.x); cur.y = fmaxf(cur.y, s.y);
            cur.z = fmaxf(cur.z, s.z); cur.w = fmaxf(cur.w, s.w);
            *op = cur;
        }
    }
}

// ---------------- the persistent cooperative kernel ----------------------------------
__global__ __launch_bounds__(NTHR, 2) void dnc_all(
    const float* __restrict__ x, const float* __restrict__ mem0,
    const float* __restrict__ Wy, const float* __restrict__ WE, const float* __restrict__ Wr,
    const float* __restrict__ Wih0, const float* __restrict__ Whh0,
    const float* __restrict__ bih0, const float* __restrict__ bhh0,
    const float* __restrict__ Wih1, const float* __restrict__ Whh1,
    const float* __restrict__ bih1, const float* __restrict__ bhh1,
    float* __restrict__ out, float* __restrict__ ws)
{
    cg::grid_group grid = cg::this_grid();
    const int bid = blockIdx.x, tid = threadIdx.x;
    const int lane = tid & 63, wid = tid >> 6;

    __shared__ __align__(16) float smf[256*36];   // 36864 B union buffer
    __shared__ float sred[8];
    __shared__ float saux[640];

    float* M      = ws;
    float* hstate = M + (size_t)BSZ*1024*64;   // ---- zero block start
    float* cstate = hstate + 4*BSZ*HD;
    float* ubuf   = cstate + 4*BSZ*HD;
    float* lww    = ubuf + BSZ*1024;
    float* lrw    = lww + BSZ*1024;
    float* lrv    = lrw + BSZ*1024*4;          // ---- zero block end (335872 floats)
    float* bnx    = lrv + BSZ*256;
    float* lin1   = bnx + (size_t)TT*BSZ*XD;
    float* gpart  = lin1 + BSZ*1024;
    float* flat   = gpart + (size_t)2*GKS*BSZ*2048;
    float* vtp    = flat + BSZ*2048;
    float* ep     = vtp + (size_t)VKS*BSZ*VT;
    float* iv     = ep + (size_t)VKS*BSZ*ET;
    float* allocw = iv + BSZ*ET;
    float* scw    = allocw + BSZ*1024;
    float* scr    = scw + BSZ*1024;
    float* rvp    = scr + (size_t)BSZ*4*1024;

    // ---- setup: M copy, zero state, batchnorm(x) for all t ----
    {
        const size_t NT = (size_t)NBLK*NTHR;
        const float4* s4 = (const float4*)mem0;
        float4* d4 = (float4*)M;
        for (size_t i = (size_t)bid*NTHR + tid; i < (size_t)BSZ*1024*64/4; i += NT) d4[i] = s4[i];
        for (size_t i = (size_t)bid*NTHR + tid; i < 335872; i += NT) hstate[i] = 0.f;
        int u = bid*NTHR + tid;
        if (u < TT*XD){
            int t = u >> 7, k = u & 127;
            float vals[BSZ]; float s = 0.f;
            #pragma unroll
            for (int b = 0; b < BSZ; ++b){ vals[b] = x[(b*TT + t)*XD + k]; s += vals[b]; }
            float mean = s*(1.f/BSZ); float ss = 0.f;
            #pragma unroll
            for (int b = 0; b < BSZ; ++b){ float d = vals[b]-mean; ss += d*d; }
            float inv = 1.f/sqrtf(ss*(1.f/BSZ) + 1e-5f);
            #pragma unroll
            for (int b = 0; b < BSZ; ++b) bnx[((size_t)t*BSZ + b)*XD + k] = (vals[b]-mean)*inv;
        }
    }
    grid.sync();

    for (int t = 0; t < TT; ++t){
        gemm_phase(bnx + (size_t)t*BSZ*XD, XD, lrv, 256, hstate, Wih0, Whh0, gpart, bid, tid, smf);
        grid.sync();
        gates_phase(gpart, bih0, bhh0, cstate, hstate, flat, lin1, 0, bid, tid);
        grid.sync();
        gemm_phase(lin1, 1024, (const float*)0, 0, hstate + 2*BSZ*HD, Wih1, Whh1, gpart, bid, tid, smf);
        grid.sync();
        gates_phase(gpart, bih1, bhh1, cstate, hstate, flat, (float*)0, 1, bid, tid);
        grid.sync();
        gemv_phase(flat, Wy, WE, vtp, ep, bid, tid, smf);
        grid.sync();
        ln_phase(ep, iv, bid, tid, sred);
        grid.sync();
        sortcw_phase(iv, lrw, lww, ubuf, allocw, M, scw, bid, tid, lane, wid, smf, saux);
        grid.sync();
        memup_phase(M, scw, allocw, iv, lww, scr, bid, tid, sred, saux);
        grid.sync();
        rv_phase(M, scr, lrw, rvp, bid, tid, lane, wid, sred, saux, smf);
        grid.sync();
        yfin_phase(rvp, Wr, vtp, lrv, out, t, bid, tid, smf);
        grid.sync();
    }
}

extern "C" void kernel_launch(void* const* d_in, const int* in_sizes, int n_in,
                              void* d_out, int out_size, void* d_ws, size_t ws_size,
                              hipStream_t stream){
    const float* x      = (const float*)d_in[0];
    const float* mem0   = (const float*)d_in[1];
    const float* Wy     = (const float*)d_in[2];
    const float* WE     = (const float*)d_in[3];
    const float* Wr     = (const float*)d_in[4];
    const float* Wih0   = (const float*)d_in[5];
    const float* Whh0   = (const float*)d_in[6];
    const float* bih0   = (const float*)d_in[7];
    const float* bhh0   = (const float*)d_in[8];
    const float* Wih1   = (const float*)d_in[9];
    const float* Whh1   = (const float*)d_in[10];
    const float* bih1   = (const float*)d_in[11];
    const float* bhh1   = (const float*)d_in[12];
    float* out = (float*)d_out;
    float* ws  = (float*)d_ws;

    void* args[] = { (void*)&x, (void*)&mem0, (void*)&Wy, (void*)&WE, (void*)&Wr,
                     (void*)&Wih0, (void*)&Whh0, (void*)&bih0, (void*)&bhh0,
                     (void*)&Wih1, (void*)&Whh1, (void*)&bih1, (void*)&bhh1,
                     (void*)&out, (void*)&ws };
    (void)hipLaunchCooperativeKernel((const void*)dnc_all, dim3(NBLK), dim3(NTHR),
                                     args, 0, stream);
}

// Round 4
// 5688.404 us; speedup vs baseline: 3.1626x; 3.1626x over previous
//
#include <hip/hip_runtime.h>
#include <math.h>

#define BSZ 32
#define TT  32
#define XD  128
#define HD  512
#define VT  2048
#define ET  463
#define VKS 16

__device__ __forceinline__ float sigf(float x){ return 1.f/(1.f+expf(-x)); }
__device__ __forceinline__ float logsigf(float x){
    return (x >= 0.f) ? -log1pf(expf(-x)) : x - log1pf(expf(x));
}

// ---- 1024-thread block reductions (wave shfl + 16 partials; red[17]) ---------------
__device__ __forceinline__ float bsum(float v, float* red, int tid){
    #pragma unroll
    for (int off = 32; off > 0; off >>= 1) v += __shfl_xor(v, off);
    if ((tid & 63) == 0) red[tid >> 6] = v;
    __syncthreads();
    if (tid == 0){
        float s = red[0];
        #pragma unroll
        for (int i = 1; i < 16; ++i) s += red[i];
        red[16] = s;
    }
    __syncthreads();
    float r = red[16];
    __syncthreads();
    return r;
}
// ---- 512-thread block reductions (8 waves; red[8]) ---------------------------------
__device__ __forceinline__ float bsum512(float v, float* red, int tid){
    #pragma unroll
    for (int off = 32; off > 0; off >>= 1) v += __shfl_xor(v, off);
    if ((tid & 63) == 0) red[tid >> 6] = v;
    __syncthreads();
    float r = red[0]+red[1]+red[2]+red[3]+red[4]+red[5]+red[6]+red[7];
    __syncthreads();
    return r;
}
__device__ __forceinline__ float bmax512(float v, float* red, int tid){
    #pragma unroll
    for (int off = 32; off > 0; off >>= 1) v = fmaxf(v, __shfl_xor(v, off));
    if ((tid & 63) == 0) red[tid >> 6] = v;
    __syncthreads();
    float r = fmaxf(fmaxf(fmaxf(red[0],red[1]),fmaxf(red[2],red[3])),
                    fmaxf(fmaxf(red[4],red[5]),fmaxf(red[6],red[7])));
    __syncthreads();
    return r;
}

// ---------------- batchnorm of x for ALL timesteps (recurrence-independent) ---------
__global__ void dnc_bnx(const float* __restrict__ x, float* __restrict__ bnx){
    int t = blockIdx.x, k = threadIdx.x;   // 128 threads
    float vals[BSZ];
    float s = 0.f;
    #pragma unroll
    for (int b = 0; b < BSZ; ++b){ vals[b] = x[(b*TT + t)*XD + k]; s += vals[b]; }
    float mean = s * (1.f/BSZ);
    float ss = 0.f;
    #pragma unroll
    for (int b = 0; b < BSZ; ++b){ float d = vals[b]-mean; ss += d*d; }
    float inv = 1.f / sqrtf(ss*(1.f/BSZ) + 1e-5f);
    #pragma unroll
    for (int b = 0; b < BSZ; ++b) bnx[((size_t)t*BSZ + b)*XD + k] = (vals[b]-mean)*inv;
}

// ---------------- fused LSTM: full-K GEMM + gates + state update ---------------------
// grid (64 u-chunks, 2 dirs), 256 thr. thread (b = tid&31, ui = tid>>5) owns all 4
// gates of (b, u = uc*8+ui): K chunked 128-wide through LDS; epilogue writes h/c/flat.
__global__ __launch_bounds__(256) void dnc_lstm_fused(
    const float* __restrict__ srcA, int KA,
    const float* __restrict__ srcB, int KB,
    const float* __restrict__ hread,
    const float* __restrict__ Wih, const float* __restrict__ Whh,
    const float* __restrict__ bih, const float* __restrict__ bhh,
    float* __restrict__ cstate, float* __restrict__ hwrite,
    float* __restrict__ flat, float* __restrict__ lout, int l)
{
    const int uc = blockIdx.x, d = blockIdx.y;
    const int tid = threadIdx.x;
    const int b = tid & 31, ui = tid >> 5;
    const int u0 = uc*8;
    const int KIH = KA + KB;
    const int cA = KA >> 7;          // 128-wide chunks of srcA
    const int cin = KIH >> 7;        // end of input chunks
    const int nct = cin + 4;         // + HD/128 h-chunks
    __shared__ float itile[128*33];
    __shared__ __align__(16) float wtile[128*36];
    float g0=0.f, g1=0.f, g2=0.f, g3=0.f;
    for (int c = 0; c < nct; ++c){
        const float* src; int stride, kb; const float* Wb; int Kw, wcol;
        if (c < cA){ src = srcA; stride = KA; kb = c*128;
                     Wb = Wih + (size_t)d*2048*KIH; Kw = KIH; wcol = kb; }
        else if (c < cin){ src = srcB; stride = KB; kb = (c-cA)*128;
                           Wb = Wih + (size_t)d*2048*KIH; Kw = KIH; wcol = c*128; }
        else { src = hread + d*(BSZ*HD); stride = HD; kb = (c-cin)*128;
               Wb = Whh + (size_t)d*2048*512; Kw = 512; wcol = kb; }
        #pragma unroll
        for (int i = 0; i < 16; ++i){
            int idx = i*256 + tid; int row = idx >> 7, kk = idx & 127;
            itile[kk*33 + row] = src[row*stride + kb + kk];
            // row = ui*4 + xg  ->  global j = xg*512 + u0 + ui
            int j = (row & 3)*512 + u0 + (row >> 2);
            wtile[kk*36 + row] = Wb[(size_t)j*Kw + wcol + kk];
        }
        __syncthreads();
        const int ui4 = ui*4;
        #pragma unroll 4
        for (int kk = 0; kk < 128; ++kk){
            float a = itile[kk*33 + b];
            float4 w = *(const float4*)&wtile[kk*36 + ui4];
            g0 += a*w.x; g1 += a*w.y; g2 += a*w.z; g3 += a*w.w;
        }
        __syncthreads();
    }
    const int u = u0 + ui;
    g0 += bih[d*2048 + u]        + bhh[d*2048 + u];
    g1 += bih[d*2048 + 512 + u]  + bhh[d*2048 + 512 + u];
    g2 += bih[d*2048 + 1024 + u] + bhh[d*2048 + 1024 + u];
    g3 += bih[d*2048 + 1536 + u] + bhh[d*2048 + 1536 + u];
    float ig = sigf(g0), fg = sigf(g1), og = sigf(g3), gg = tanhf(g2);
    int cell = 2*l + d;
    int ci = (cell*BSZ + b)*HD + u;
    float c2 = fg*cstate[ci] + ig*gg;
    cstate[ci] = c2;
    float h = og*tanhf(c2);
    hwrite[ci] = h;
    flat[b*2048 + cell*HD + u] = h;
    if (lout) lout[b*1024 + d*HD + u] = h;
}

// ---------------- combined GEMV: flat@Wy (bx 0-15) + flat@WE (bx 16-19) --------------
__global__ void dnc_gemv2(const float* __restrict__ fin, const float* __restrict__ Wy,
                          const float* __restrict__ WE,
                          float* __restrict__ vtp, float* __restrict__ ep){
    const int bx = blockIdx.x, ksi = blockIdx.y;
    const float* Wm; float* outp; int Mdim, mb;
    if (bx < 16){ Wm = Wy; outp = vtp; Mdim = VT; mb = bx; }
    else        { Wm = WE; outp = ep;  Mdim = ET; mb = bx - 16; }
    const int tid = threadIdx.x;
    const int lane = tid & 63, bg = tid >> 6;
    const int b0 = bg*8;
    const int m0 = mb*128 + lane, m1 = m0 + 64;
    const int k0 = ksi*128;
    __shared__ __align__(16) float tile[128*36];
    #pragma unroll
    for (int i = 0; i < 16; ++i){
        int idx = i*256 + tid; int kk = idx & 127, b = idx >> 7;
        tile[kk*36 + b] = fin[b*2048 + k0 + kk];
    }
    __syncthreads();
    bool v0 = m0 < Mdim, v1 = m1 < Mdim;
    float acc[16] = {0};
    for (int kk = 0; kk < 128; ++kk){
        float4 pq = *(const float4*)&tile[kk*36 + b0];
        float4 qq = *(const float4*)&tile[kk*36 + b0 + 4];
        const float* wr = Wm + (size_t)(k0+kk)*Mdim;
        float w0 = v0 ? wr[m0] : 0.f;
        float w1 = v1 ? wr[m1] : 0.f;
        acc[0]+=pq.x*w0; acc[1]+=pq.y*w0; acc[2]+=pq.z*w0; acc[3]+=pq.w*w0;
        acc[4]+=qq.x*w0; acc[5]+=qq.y*w0; acc[6]+=qq.z*w0; acc[7]+=qq.w*w0;
        acc[8]+=pq.x*w1; acc[9]+=pq.y*w1; acc[10]+=pq.z*w1; acc[11]+=pq.w*w1;
        acc[12]+=qq.x*w1; acc[13]+=qq.y*w1; acc[14]+=qq.z*w1; acc[15]+=qq.w*w1;
    }
    if (v0){
        #pragma unroll
        for (int bb = 0; bb < 8; ++bb)
            outp[((size_t)ksi*BSZ + b0+bb)*Mdim + m0] = acc[bb];
    }
    if (v1){
        #pragma unroll
        for (int bb = 0; bb < 8; ++bb)
            outp[((size_t)ksi*BSZ + b0+bb)*Mdim + m1] = acc[8+bb];
    }
}

// ---------------- presort (blocks 0-31) || cw_score (blocks 32-63) -------------------
__global__ __launch_bounds__(1024) void dnc_presort_cw(
    const float* __restrict__ ep, const float* __restrict__ lrw,
    const float* __restrict__ lww, float* __restrict__ ubuf,
    float* __restrict__ iv, float* __restrict__ allocw,
    const float* __restrict__ M, float* __restrict__ scw)
{
    const int bid = blockIdx.x, tid = threadIdx.x;
    const int lane = tid & 63, wid = tid >> 6;
    __shared__ float red[32];
    __shared__ float ivS[464];
    __shared__ unsigned long long keysS[1024];
    __shared__ float wtot[16], wpref[16];

    if (bid < 32){
        const int b = bid;
        // layernorm of WE partial sums -> iv
        float myv = 0.f;
        if (tid < ET){
            #pragma unroll
            for (int s = 0; s < VKS; ++s) myv += ep[((size_t)s*BSZ + b)*ET + tid];
        }
        float mean = bsum(myv, red, tid) * (1.f/ET);
        float dd = (tid < ET) ? (myv - mean) : 0.f;
        float var = bsum(dd*dd, red, tid) * (1.f/ET);
        float rinv = 1.f / sqrtf(var + 1e-5f);
        float ivv = (myv - mean)*rinv;
        if (tid < ET){ ivS[tid] = ivv; iv[b*ET + tid] = ivv; }
        __syncthreads();

        // usage
        const int n = tid;
        float4 lw4 = *(const float4*)&lrw[((size_t)b*1024 + n)*4];
        float f0 = sigf(ivS[453]), f1 = sigf(ivS[454]), f2 = sigf(ivS[455]), f3 = sigf(ivS[456]);
        float ret = (1.f-f0*lw4.x)*(1.f-f1*lw4.y)*(1.f-f2*lw4.z)*(1.f-f3*lw4.w);
        float uo = ubuf[b*1024+n], lwo = lww[b*1024+n];
        float un = (uo + lwo - uo*lwo)*ret;
        ubuf[b*1024+n] = un;

        // hybrid bitonic sort (LDS j>=64, shfl j<64); u>=0 so uint order == float order
        unsigned long long key = ((unsigned long long)__float_as_uint(un) << 32) | (unsigned)tid;
        for (int k = 2; k <= 1024; k <<= 1){
            int j = k >> 1;
            for (; j >= 64; j >>= 1){
                keysS[tid] = key; __syncthreads();
                unsigned long long other = keysS[tid ^ j];
                bool up = ((tid & k) == 0);
                bool takeMin = (((tid & j) == 0) == up);
                key = takeMin ? (key < other ? key : other) : (key > other ? key : other);
                __syncthreads();
            }
            for (; j >= 1; j >>= 1){
                unsigned long long other = __shfl_xor(key, j);
                bool up = ((tid & k) == 0);
                bool takeMin = (((tid & j) == 0) == up);
                key = takeMin ? (key < other ? key : other) : (key > other ? key : other);
            }
        }
        float su = __uint_as_float((unsigned)(key >> 32));
        int idxv = (int)(key & 0xffffffffu);

        // exclusive cumprod via wave shfl scan + 16 wave totals
        float p = su;
        #pragma unroll
        for (int o = 1; o < 64; o <<= 1){ float q = __shfl_up(p, o); if (lane >= o) p *= q; }
        if (lane == 63) wtot[wid] = p;
        __syncthreads();
        if (tid == 0){
            float r = 1.f;
            #pragma unroll
            for (int i = 0; i < 16; ++i){ wpref[i] = r; r *= wtot[i]; }
        }
        __syncthreads();
        float excl = __shfl_up(p, 1); if (lane == 0) excl = 1.f;
        float cpx = excl * wpref[wid];
        allocw[b*1024 + idxv] = (1.f - su)*cpx;
    } else {
        const int b = bid - 32;
        // mini-layernorm recompute (cheap; breaks same-stage dependency on iv)
        float myv = 0.f;
        if (tid < ET){
            #pragma unroll
            for (int s = 0; s < VKS; ++s) myv += ep[((size_t)s*BSZ + b)*ET + tid];
        }
        float mean = bsum(myv, red, tid) * (1.f/ET);
        float dd = (tid < ET) ? (myv - mean) : 0.f;
        float var = bsum(dd*dd, red, tid) * (1.f/ET);
        float rinv = 1.f / sqrtf(var + 1e-5f);
        float ivv = (myv - mean)*rinv;
        if (tid >= 260 && tid < 324) ivS[tid - 260] = ivv;   // write key
        if (tid == 324) ivS[64] = 1.f - logsigf(ivv);        // wbeta
        __syncthreads();
        float ksq = 0.f;
        #pragma unroll
        for (int w = 0; w < 64; ++w) ksq += ivS[w]*ivS[w];
        float kden = sqrtf(ksq) + 1e-8f;
        float wb = ivS[64];
        const float* Mrow = M + ((size_t)b*1024 + tid)*64;
        float dot = 0.f, msq = 0.f;
        #pragma unroll
        for (int w = 0; w < 64; w += 4){
            float4 mv = *(const float4*)(Mrow + w);
            dot += mv.x*ivS[w] + mv.y*ivS[w+1] + mv.z*ivS[w+2] + mv.w*ivS[w+3];
            msq += mv.x*mv.x + mv.y*mv.y + mv.z*mv.z + mv.w*mv.w;
        }
        scw[b*1024 + tid] = wb*dot/((sqrtf(msq) + 1e-8f)*kden);
    }
}

// ---------------- memup (64 blks x 512): cw softmax+ww fused, M update, rd scores ----
__global__ __launch_bounds__(512) void dnc_memup(float* __restrict__ M,
    const float* __restrict__ scw, const float* __restrict__ allocw,
    const float* __restrict__ iv, float* __restrict__ lww, float* __restrict__ scr)
{
    const int bid = blockIdx.x, tid = threadIdx.x;
    __shared__ float red[8];
    __shared__ float aux[392];
    const int b = bid >> 1, half = bid & 1;
    const int n = half*512 + tid;
    // content-write softmax over all 1024 n (redundant per half-block, cheap)
    float s0 = scw[b*1024 + tid], s1 = scw[b*1024 + 512 + tid];
    float mx = bmax512(fmaxf(s0, s1), red, tid);
    float tot = bsum512(expf(s0-mx) + expf(s1-mx), red, tid);
    float own = half ? s1 : s0;
    float cwv = expf(own - mx)/tot;
    float ag = sigf(iv[b*ET + 457]), wg = sigf(iv[b*ET + 458]);
    float wwv = wg*(ag*allocw[b*1024 + n] + (1.f-ag)*cwv);
    lww[b*1024 + n] = wwv;
    // stage erase [0..63], wvec [64..127], rkn [128..383], nrm [384..387], rb [388..391]
    if (tid < 64){ aux[tid] = sigf(iv[b*ET + 325 + tid]); aux[64+tid] = iv[b*ET + 389 + tid]; }
    if (tid >= 64 && tid < 320) aux[64 + tid] = iv[b*ET + (tid - 64)];
    __syncthreads();
    if (tid < 4){
        float s = 0.f;
        #pragma unroll
        for (int w = 0; w < 64; ++w){ float v = aux[128 + w*4 + tid]; s += v*v; }
        aux[384 + tid] = sqrtf(s) + 1e-8f;
        aux[388 + tid] = 1.f - logsigf(iv[b*ET + 256 + tid]);
    }
    __syncthreads();
    if (tid < 256) aux[128 + tid] = aux[128 + tid] / aux[384 + (tid & 3)];
    __syncthreads();
    float* Mrow = M + ((size_t)b*1024 + n)*64;
    float dr0=0.f, dr1=0.f, dr2=0.f, dr3=0.f, msq2=0.f;
    #pragma unroll
    for (int w = 0; w < 64; w += 4){
        float4 mv = *(const float4*)(Mrow + w);
        mv.x = mv.x*(1.f - wwv*aux[w+0]) + wwv*aux[64+w+0];
        mv.y = mv.y*(1.f - wwv*aux[w+1]) + wwv*aux[64+w+1];
        mv.z = mv.z*(1.f - wwv*aux[w+2]) + wwv*aux[64+w+2];
        mv.w = mv.w*(1.f - wwv*aux[w+3]) + wwv*aux[64+w+3];
        *(float4*)(Mrow + w) = mv;
        msq2 += mv.x*mv.x + mv.y*mv.y + mv.z*mv.z + mv.w*mv.w;
        dr0 += mv.x*aux[128+(w+0)*4+0] + mv.y*aux[128+(w+1)*4+0] + mv.z*aux[128+(w+2)*4+0] + mv.w*aux[128+(w+3)*4+0];
        dr1 += mv.x*aux[128+(w+0)*4+1] + mv.y*aux[128+(w+1)*4+1] + mv.z*aux[128+(w+2)*4+1] + mv.w*aux[128+(w+3)*4+1];
        dr2 += mv.x*aux[128+(w+0)*4+2] + mv.y*aux[128+(w+1)*4+2] + mv.z*aux[128+(w+2)*4+2] + mv.w*aux[128+(w+3)*4+2];
        dr3 += mv.x*aux[128+(w+0)*4+3] + mv.y*aux[128+(w+1)*4+3] + mv.z*aux[128+(w+2)*4+3] + mv.w*aux[128+(w+3)*4+3];
    }
    float den = sqrtf(msq2) + 1e-8f;
    scr[((size_t)(b*4 + 0))*1024 + n] = aux[388]*dr0/den;
    scr[((size_t)(b*4 + 1))*1024 + n] = aux[389]*dr1/den;
    scr[((size_t)(b*4 + 2))*1024 + n] = aux[390]*dr2/den;
    scr[((size_t)(b*4 + 3))*1024 + n] = aux[391]*dr3/den;
}

// ---------------- rv (64 blks x 512): read softmax fused, writes lrw + rvp -----------
__global__ __launch_bounds__(512) void dnc_rv(const float* __restrict__ M,
    const float* __restrict__ scr, float* __restrict__ lrw, float* __restrict__ rvp)
{
    const int bid = blockIdx.x, tid = threadIdx.x;
    const int lane = tid & 63, wid = tid >> 6;
    __shared__ float red[8];
    __shared__ float aux[8];
    __shared__ float rwS[2048];
    const int b = bid >> 1, half = bid & 1;
    // softmax denominators per r over all 1024 n: r_ = tid>>7, 8 n per thread
    const int r_ = tid >> 7;
    const int i8 = tid & 127;
    const float* srow = scr + ((size_t)(b*4 + r_))*1024;
    float vloc[8];
    float lm = -1e30f;
    #pragma unroll
    for (int i = 0; i < 8; ++i){ vloc[i] = srow[i8*8 + i]; lm = fmaxf(lm, vloc[i]); }
    #pragma unroll
    for (int off = 32; off > 0; off >>= 1) lm = fmaxf(lm, __shfl_xor(lm, off));
    if (lane == 0) red[wid] = lm;
    __syncthreads();
    if (tid < 4) aux[tid] = fmaxf(red[2*tid], red[2*tid+1]);
    __syncthreads();
    float mxr = aux[r_];
    float lsum = 0.f;
    #pragma unroll
    for (int i = 0; i < 8; ++i) lsum += expf(vloc[i] - mxr);
    #pragma unroll
    for (int off = 32; off > 0; off >>= 1) lsum += __shfl_xor(lsum, off);
    if (lane == 0) red[wid] = lsum;
    __syncthreads();
    if (tid < 4) aux[4+tid] = red[2*tid] + red[2*tid+1];
    __syncthreads();
    // rw for own half (512 n x 4 r): stage LDS + write global lrw
    #pragma unroll
    for (int i = 0; i < 4; ++i){
        int idx = i*512 + tid;
        int j = idx >> 2, r = idx & 3;
        int n = half*512 + j;
        float v = expf(scr[((size_t)(b*4 + r))*1024 + n] - aux[r]) / aux[4+r];
        rwS[j*4 + r] = v;
        lrw[((size_t)(b*1024 + n))*4 + r] = v;
    }
    __syncthreads();
    // rv partials over own half's two n-quarters
    const int q = tid >> 8;
    const int r = (tid >> 6) & 3, w = tid & 63;
    const int ns = half*2 + q;
    const float* Mb = M + ((size_t)b*1024 + ns*256)*64;
    const float* rb = rwS + (q*256)*4 + r;
    float acc = 0.f;
    for (int i = 0; i < 256; ++i)
        acc += Mb[(size_t)i*64 + w] * rb[i*4];
    rvp[((size_t)(ns*BSZ + b))*256 + r*64 + w] = acc;
}

// ---------------- final: sum rvp -> lrv(tile+global), yt = rv@Wr + vtp; out max ------
__global__ void dnc_yfin(const float* __restrict__ rvp, const float* __restrict__ Wr,
                         const float* __restrict__ vtp, float* __restrict__ lrv,
                         float* __restrict__ out, int t){
    const int tid = threadIdx.x;
    const int mg = tid & 31, bg = tid >> 5;
    const int m0 = blockIdx.x*128 + mg*4;
    const int b0 = bg*4;
    __shared__ __align__(16) float lt[256*36];   // lrv^T [k][b]; k = w*4+r
    #pragma unroll
    for (int i = 0; i < 32; ++i){
        int idx = i*256 + tid; int k = idx & 255, b = idx >> 8;
        int w = k >> 2, r = k & 3;
        int ksrc = r*64 + w;
        float s = 0.f;
        #pragma unroll
        for (int c = 0; c < 4; ++c) s += rvp[((size_t)(c*BSZ + b))*256 + ksrc];
        lt[k*36 + b] = s;
        if (blockIdx.x == 0) lrv[b*256 + k] = s;
    }
    __syncthreads();
    float acc[4][4] = {{0}};
    for (int kk = 0; kk < 256; ++kk){
        float4 av = *(const float4*)&lt[kk*36 + b0];
        float4 wv = *(const float4*)&Wr[(size_t)kk*VT + m0];
        acc[0][0]+=av.x*wv.x; acc[0][1]+=av.x*wv.y; acc[0][2]+=av.x*wv.z; acc[0][3]+=av.x*wv.w;
        acc[1][0]+=av.y*wv.x; acc[1][1]+=av.y*wv.y; acc[1][2]+=av.y*wv.z; acc[1][3]+=av.y*wv.w;
        acc[2][0]+=av.z*wv.x; acc[2][1]+=av.z*wv.y; acc[2][2]+=av.z*wv.z; acc[2][3]+=av.z*wv.w;
        acc[3][0]+=av.w*wv.x; acc[3][1]+=av.w*wv.y; acc[3][2]+=av.w*wv.z; acc[3][3]+=av.w*wv.w;
    }
    #pragma unroll
    for (int bi = 0; bi < 4; ++bi){
        int b = b0 + bi;
        float4 s = make_float4(acc[bi][0], acc[bi][1], acc[bi][2], acc[bi][3]);
        #pragma unroll
        for (int sp = 0; sp < VKS; ++sp){
            float4 vp = *(const float4*)&vtp[((size_t)sp*BSZ + b)*VT + m0];
            s.x += vp.x; s.y += vp.y; s.z += vp.z; s.w += vp.w;
        }
        float4* op = (float4*)&out[(size_t)b*VT + m0];
        if (t == 0){ *op = s; }
        else {
            float4 cur = *op;
            cur.x = fmaxf(cur.x, s.x); cur.y = fmaxf(cur.y, s.y);
            cur.z = fmaxf(cur.z, s.z); cur.w = fmaxf(cur.w, s.w);
            *op = cur;
        }
    }
}

extern "C" void kernel_launch(void* const* d_in, const int* in_sizes, int n_in,
                              void* d_out, int out_size, void* d_ws, size_t ws_size,
                              hipStream_t stream){
    const float* x      = (const float*)d_in[0];
    const float* mem0   = (const float*)d_in[1];
    const float* Wy     = (const float*)d_in[2];
    const float* WE     = (const float*)d_in[3];
    const float* Wr     = (const float*)d_in[4];
    const float* Wih0   = (const float*)d_in[5];
    const float* Whh0   = (const float*)d_in[6];
    const float* bih0   = (const float*)d_in[7];
    const float* bhh0   = (const float*)d_in[8];
    const float* Wih1   = (const float*)d_in[9];
    const float* Whh1   = (const float*)d_in[10];
    const float* bih1   = (const float*)d_in[11];
    const float* bhh1   = (const float*)d_in[12];
    float* out = (float*)d_out;

    float* p = (float*)d_ws;
    float* M       = p; p += (size_t)BSZ*1024*64;
    float* hstate0 = p; p += 4*BSZ*HD;     // zero block start
    float* hstate1 = p; p += 4*BSZ*HD;
    float* cstate  = p; p += 4*BSZ*HD;
    float* ubuf    = p; p += BSZ*1024;
    float* lww     = p; p += BSZ*1024;
    float* lrw     = p; p += BSZ*1024*4;
    float* lrv     = p; p += BSZ*256;      // zero block end
    float* bnx     = p; p += (size_t)TT*BSZ*XD;
    float* lin1    = p; p += BSZ*1024;
    float* flat    = p; p += BSZ*2048;
    float* vtp     = p; p += (size_t)VKS*BSZ*VT;
    float* ep      = p; p += (size_t)VKS*BSZ*ET;
    float* iv      = p; p += BSZ*ET;
    float* allocw  = p; p += BSZ*1024;
    float* scw     = p; p += BSZ*1024;
    float* scr     = p; p += (size_t)BSZ*4*1024;
    float* rvp     = p; p += 4*BSZ*256;

    (void)hipMemcpyAsync(M, mem0, (size_t)BSZ*1024*64*sizeof(float), hipMemcpyDeviceToDevice, stream);
    size_t zfloats = (size_t)(4*BSZ*HD)*3 + BSZ*1024*2 + BSZ*1024*4 + BSZ*256;
    (void)hipMemsetAsync(hstate0, 0, zfloats*sizeof(float), stream);

    dnc_bnx<<<TT, 128, 0, stream>>>(x, bnx);

    for (int t = 0; t < TT; ++t){
        const float* hr = (t & 1) ? hstate1 : hstate0;
        float*       hw = (t & 1) ? hstate0 : hstate1;
        dnc_lstm_fused<<<dim3(64,2), 256, 0, stream>>>(bnx + (size_t)t*BSZ*XD, XD,
            lrv, 256, hr, Wih0, Whh0, bih0, bhh0, cstate, hw, flat, lin1, 0);
        dnc_lstm_fused<<<dim3(64,2), 256, 0, stream>>>(lin1, 1024,
            nullptr, 0, hr + 2*BSZ*HD, Wih1, Whh1, bih1, bhh1, cstate, hw, flat, nullptr, 1);
        dnc_gemv2<<<dim3(20,VKS), 256, 0, stream>>>(flat, Wy, WE, vtp, ep);
        dnc_presort_cw<<<64, 1024, 0, stream>>>(ep, lrw, lww, ubuf, iv, allocw, M, scw);
        dnc_memup<<<64, 512, 0, stream>>>(M, scw, allocw, iv, lww, scr);
        dnc_rv<<<64, 512, 0, stream>>>(M, scr, lrw, rvp);
        dnc_yfin<<<16, 256, 0, stream>>>(rvp, Wr, vtp, lrv, out, t);
    }
}

// Round 6
// 5178.735 us; speedup vs baseline: 3.4738x; 1.0984x over previous
//
#include <hip/hip_runtime.h>
#include <math.h>

#define BSZ 32
#define TT  32
#define XD  128
#define HD  512
#define VT  2048
#define ET  463
#define VKS 16

__device__ __forceinline__ float sigf(float x){ return 1.f/(1.f+expf(-x)); }
__device__ __forceinline__ float logsigf(float x){
    return (x >= 0.f) ? -log1pf(expf(-x)) : x - log1pf(expf(x));
}

// ---- 1024-thread block reductions (wave shfl + 16 partials; red[17+]) --------------
__device__ __forceinline__ float bsum(float v, float* red, int tid){
    #pragma unroll
    for (int off = 32; off > 0; off >>= 1) v += __shfl_xor(v, off);
    if ((tid & 63) == 0) red[tid >> 6] = v;
    __syncthreads();
    if (tid == 0){
        float s = red[0];
        #pragma unroll
        for (int i = 1; i < 16; ++i) s += red[i];
        red[16] = s;
    }
    __syncthreads();
    float r = red[16];
    __syncthreads();
    return r;
}
__device__ __forceinline__ float bmax(float v, float* red, int tid){
    #pragma unroll
    for (int off = 32; off > 0; off >>= 1) v = fmaxf(v, __shfl_xor(v, off));
    if ((tid & 63) == 0) red[tid >> 6] = v;
    __syncthreads();
    if (tid == 0){
        float s = red[0];
        #pragma unroll
        for (int i = 1; i < 16; ++i) s = fmaxf(s, red[i]);
        red[16] = s;
    }
    __syncthreads();
    float r = red[16];
    __syncthreads();
    return r;
}

// ---------------- batchnorm of x for ALL timesteps (recurrence-independent) ---------
__global__ void dnc_bnx(const float* __restrict__ x, float* __restrict__ bnx){
    int t = blockIdx.x, k = threadIdx.x;   // 128 threads
    float vals[BSZ];
    float s = 0.f;
    #pragma unroll
    for (int b = 0; b < BSZ; ++b){ vals[b] = x[(b*TT + t)*XD + k]; s += vals[b]; }
    float mean = s * (1.f/BSZ);
    float ss = 0.f;
    #pragma unroll
    for (int b = 0; b < BSZ; ++b){ float d = vals[b]-mean; ss += d*d; }
    float inv = 1.f / sqrtf(ss*(1.f/BSZ) + 1e-5f);
    #pragma unroll
    for (int b = 0; b < BSZ; ++b) bnx[((size_t)t*BSZ + b)*XD + k] = (vals[b]-mean)*inv;
}

// ---------------- fused LSTM: full-K GEMM + gates + state update ---------------------
// grid (64 u-chunks, 2 dirs), 256 thr. thread (b = tid&31, ui = tid>>5) owns all 4
// gates of (b, u = uc*8+ui): K chunked 128-wide through LDS; epilogue writes h/c/flat.
__global__ __launch_bounds__(256) void dnc_lstm_fused(
    const float* __restrict__ srcA, int KA,
    const float* __restrict__ srcB, int KB,
    const float* __restrict__ hread,
    const float* __restrict__ Wih, const float* __restrict__ Whh,
    const float* __restrict__ bih, const float* __restrict__ bhh,
    float* __restrict__ cstate, float* __restrict__ hwrite,
    float* __restrict__ flat, float* __restrict__ lout, int l)
{
    const int uc = blockIdx.x, d = blockIdx.y;
    const int tid = threadIdx.x;
    const int b = tid & 31, ui = tid >> 5;
    const int u0 = uc*8;
    const int KIH = KA + KB;
    const int cA = KA >> 7;          // 128-wide chunks of srcA
    const int cin = KIH >> 7;        // end of input chunks
    const int nct = cin + 4;         // + HD/128 h-chunks
    __shared__ float itile[128*33];
    __shared__ __align__(16) float wtile[128*36];
    float g0=0.f, g1=0.f, g2=0.f, g3=0.f;
    for (int c = 0; c < nct; ++c){
        const float* src; int stride, kb; const float* Wb; int Kw, wcol;
        if (c < cA){ src = srcA; stride = KA; kb = c*128;
                     Wb = Wih + (size_t)d*2048*KIH; Kw = KIH; wcol = kb; }
        else if (c < cin){ src = srcB; stride = KB; kb = (c-cA)*128;
                           Wb = Wih + (size_t)d*2048*KIH; Kw = KIH; wcol = c*128; }
        else { src = hread + d*(BSZ*HD); stride = HD; kb = (c-cin)*128;
               Wb = Whh + (size_t)d*2048*512; Kw = 512; wcol = kb; }
        #pragma unroll
        for (int i = 0; i < 16; ++i){
            int idx = i*256 + tid; int row = idx >> 7, kk = idx & 127;
            itile[kk*33 + row] = src[row*stride + kb + kk];
            // row = ui*4 + xg  ->  global j = xg*512 + u0 + ui
            int j = (row & 3)*512 + u0 + (row >> 2);
            wtile[kk*36 + row] = Wb[(size_t)j*Kw + wcol + kk];
        }
        __syncthreads();
        const int ui4 = ui*4;
        #pragma unroll 4
        for (int kk = 0; kk < 128; ++kk){
            float a = itile[kk*33 + b];
            float4 w = *(const float4*)&wtile[kk*36 + ui4];
            g0 += a*w.x; g1 += a*w.y; g2 += a*w.z; g3 += a*w.w;
        }
        __syncthreads();
    }
    const int u = u0 + ui;
    g0 += bih[d*2048 + u]        + bhh[d*2048 + u];
    g1 += bih[d*2048 + 512 + u]  + bhh[d*2048 + 512 + u];
    g2 += bih[d*2048 + 1024 + u] + bhh[d*2048 + 1024 + u];
    g3 += bih[d*2048 + 1536 + u] + bhh[d*2048 + 1536 + u];
    float ig = sigf(g0), fg = sigf(g1), og = sigf(g3), gg = tanhf(g2);
    int cell = 2*l + d;
    int ci = (cell*BSZ + b)*HD + u;
    float c2 = fg*cstate[ci] + ig*gg;
    cstate[ci] = c2;
    float h = og*tanhf(c2);
    hwrite[ci] = h;
    flat[b*2048 + cell*HD + u] = h;
    if (lout) lout[b*1024 + d*HD + u] = h;
}

// ---------------- combined GEMV: flat@Wy (bx 0-15) + flat@WE (bx 16-19) --------------
__global__ void dnc_gemv2(const float* __restrict__ fin, const float* __restrict__ Wy,
                          const float* __restrict__ WE,
                          float* __restrict__ vtp, float* __restrict__ ep){
    const int bx = blockIdx.x, ksi = blockIdx.y;
    const float* Wm; float* outp; int Mdim, mb;
    if (bx < 16){ Wm = Wy; outp = vtp; Mdim = VT; mb = bx; }
    else        { Wm = WE; outp = ep;  Mdim = ET; mb = bx - 16; }
    const int tid = threadIdx.x;
    const int lane = tid & 63, bg = tid >> 6;
    const int b0 = bg*8;
    const int m0 = mb*128 + lane, m1 = m0 + 64;
    const int k0 = ksi*128;
    __shared__ __align__(16) float tile[128*36];
    #pragma unroll
    for (int i = 0; i < 16; ++i){
        int idx = i*256 + tid; int kk = idx & 127, b = idx >> 7;
        tile[kk*36 + b] = fin[b*2048 + k0 + kk];
    }
    __syncthreads();
    bool v0 = m0 < Mdim, v1 = m1 < Mdim;
    float acc[16] = {0};
    for (int kk = 0; kk < 128; ++kk){
        float4 pq = *(const float4*)&tile[kk*36 + b0];
        float4 qq = *(const float4*)&tile[kk*36 + b0 + 4];
        const float* wr = Wm + (size_t)(k0+kk)*Mdim;
        float w0 = v0 ? wr[m0] : 0.f;
        float w1 = v1 ? wr[m1] : 0.f;
        acc[0]+=pq.x*w0; acc[1]+=pq.y*w0; acc[2]+=pq.z*w0; acc[3]+=pq.w*w0;
        acc[4]+=qq.x*w0; acc[5]+=qq.y*w0; acc[6]+=qq.z*w0; acc[7]+=qq.w*w0;
        acc[8]+=pq.x*w1; acc[9]+=pq.y*w1; acc[10]+=pq.z*w1; acc[11]+=pq.w*w1;
        acc[12]+=qq.x*w1; acc[13]+=qq.y*w1; acc[14]+=qq.z*w1; acc[15]+=qq.w*w1;
    }
    if (v0){
        #pragma unroll
        for (int bb = 0; bb < 8; ++bb)
            outp[((size_t)ksi*BSZ + b0+bb)*Mdim + m0] = acc[bb];
    }
    if (v1){
        #pragma unroll
        for (int bb = 0; bb < 8; ++bb)
            outp[((size_t)ksi*BSZ + b0+bb)*Mdim + m1] = acc[8+bb];
    }
}

// ---------------- presort (blocks 0-31) || cw_score (blocks 32-63) -------------------
__global__ __launch_bounds__(1024) void dnc_presort_cw(
    const float* __restrict__ ep, const float* __restrict__ lrw,
    const float* __restrict__ lww, float* __restrict__ ubuf,
    float* __restrict__ iv, float* __restrict__ allocw,
    const float* __restrict__ M, float* __restrict__ scw)
{
    const int bid = blockIdx.x, tid = threadIdx.x;
    const int lane = tid & 63, wid = tid >> 6;
    __shared__ float red[32];
    __shared__ float ivS[464];
    __shared__ unsigned long long keysS[1024];
    __shared__ float wtot[16], wpref[16];

    if (bid < 32){
        const int b = bid;
        // layernorm of WE partial sums -> iv
        float myv = 0.f;
        if (tid < ET){
            #pragma unroll
            for (int s = 0; s < VKS; ++s) myv += ep[((size_t)s*BSZ + b)*ET + tid];
        }
        float mean = bsum(myv, red, tid) * (1.f/ET);
        float dd = (tid < ET) ? (myv - mean) : 0.f;
        float var = bsum(dd*dd, red, tid) * (1.f/ET);
        float rinv = 1.f / sqrtf(var + 1e-5f);
        float ivv = (myv - mean)*rinv;
        if (tid < ET){ ivS[tid] = ivv; iv[b*ET + tid] = ivv; }
        __syncthreads();

        // usage
        const int n = tid;
        float4 lw4 = *(const float4*)&lrw[((size_t)b*1024 + n)*4];
        float f0 = sigf(ivS[453]), f1 = sigf(ivS[454]), f2 = sigf(ivS[455]), f3 = sigf(ivS[456]);
        float ret = (1.f-f0*lw4.x)*(1.f-f1*lw4.y)*(1.f-f2*lw4.z)*(1.f-f3*lw4.w);
        float uo = ubuf[b*1024+n], lwo = lww[b*1024+n];
        float un = (uo + lwo - uo*lwo)*ret;
        ubuf[b*1024+n] = un;

        // hybrid bitonic sort (LDS j>=64, shfl j<64); u>=0 so uint order == float order
        unsigned long long key = ((unsigned long long)__float_as_uint(un) << 32) | (unsigned)tid;
        for (int k = 2; k <= 1024; k <<= 1){
            int j = k >> 1;
            for (; j >= 64; j >>= 1){
                keysS[tid] = key; __syncthreads();
                unsigned long long other = keysS[tid ^ j];
                bool up = ((tid & k) == 0);
                bool takeMin = (((tid & j) == 0) == up);
                key = takeMin ? (key < other ? key : other) : (key > other ? key : other);
                __syncthreads();
            }
            for (; j >= 1; j >>= 1){
                unsigned long long other = __shfl_xor(key, j);
                bool up = ((tid & k) == 0);
                bool takeMin = (((tid & j) == 0) == up);
                key = takeMin ? (key < other ? key : other) : (key > other ? key : other);
            }
        }
        float su = __uint_as_float((unsigned)(key >> 32));
        int idxv = (int)(key & 0xffffffffu);

        // exclusive cumprod via wave shfl scan + 16 wave totals
        float p = su;
        #pragma unroll
        for (int o = 1; o < 64; o <<= 1){ float q = __shfl_up(p, o); if (lane >= o) p *= q; }
        if (lane == 63) wtot[wid] = p;
        __syncthreads();
        if (tid == 0){
            float r = 1.f;
            #pragma unroll
            for (int i = 0; i < 16; ++i){ wpref[i] = r; r *= wtot[i]; }
        }
        __syncthreads();
        float excl = __shfl_up(p, 1); if (lane == 0) excl = 1.f;
        float cpx = excl * wpref[wid];
        allocw[b*1024 + idxv] = (1.f - su)*cpx;
    } else {
        const int b = bid - 32;
        // mini-layernorm recompute (cheap; breaks same-stage dependency on iv)
        float myv = 0.f;
        if (tid < ET){
            #pragma unroll
            for (int s = 0; s < VKS; ++s) myv += ep[((size_t)s*BSZ + b)*ET + tid];
        }
        float mean = bsum(myv, red, tid) * (1.f/ET);
        float dd = (tid < ET) ? (myv - mean) : 0.f;
        float var = bsum(dd*dd, red, tid) * (1.f/ET);
        float rinv = 1.f / sqrtf(var + 1e-5f);
        float ivv = (myv - mean)*rinv;
        if (tid >= 260 && tid < 324) ivS[tid - 260] = ivv;   // write key
        if (tid == 324) ivS[64] = 1.f - logsigf(ivv);        // wbeta
        __syncthreads();
        float ksq = 0.f;
        #pragma unroll
        for (int w = 0; w < 64; ++w) ksq += ivS[w]*ivS[w];
        float kden = sqrtf(ksq) + 1e-8f;
        float wb = ivS[64];
        const float* Mrow = M + ((size_t)b*1024 + tid)*64;
        float dot = 0.f, msq = 0.f;
        #pragma unroll
        for (int w = 0; w < 64; w += 4){
            float4 mv = *(const float4*)(Mrow + w);
            dot += mv.x*ivS[w] + mv.y*ivS[w+1] + mv.z*ivS[w+2] + mv.w*ivS[w+3];
            msq += mv.x*mv.x + mv.y*mv.y + mv.z*mv.z + mv.w*mv.w;
        }
        scw[b*1024 + tid] = wb*dot/((sqrtf(msq) + 1e-8f)*kden);
    }
}

// ------- fused memory tail (32 blks x 1024): cw-softmax+ww, M update, read scores,
//         read softmax, read vectors. scr lives in LDS; M re-read via same-CU L1/L2. --
__global__ __launch_bounds__(1024) void dnc_memup_rv(
    float* __restrict__ M, const float* __restrict__ scw,
    const float* __restrict__ allocw, const float* __restrict__ iv,
    float* __restrict__ lww, float* __restrict__ lrw, float* __restrict__ lrv)
{
    const int b = blockIdx.x, tid = threadIdx.x;
    const int lane = tid & 63, wid = tid >> 6;
    __shared__ float red[32];
    __shared__ float aux[400];
    __shared__ float pS[4096];     // [r][n] scores then rw
    __shared__ float rvS[1024];
    const int n = tid;

    // ---- content-write softmax + ww ----
    float s = scw[b*1024 + n];
    float mx = bmax(s, red, tid);
    float tot = bsum(expf(s - mx), red, tid);
    float cwv = expf(s - mx)/tot;
    float ag = sigf(iv[b*ET + 457]), wg = sigf(iv[b*ET + 458]);
    float wwv = wg*(ag*allocw[b*1024 + n] + (1.f-ag)*cwv);
    lww[b*1024 + n] = wwv;

    // stage erase[0..63], wvec[64..127], rkn[128..383], nrm[384..387], rb[392..395]
    if (tid < 64){ aux[tid] = sigf(iv[b*ET + 325 + tid]); aux[64+tid] = iv[b*ET + 389 + tid]; }
    if (tid >= 64 && tid < 320) aux[64 + tid] = iv[b*ET + (tid - 64)];
    if (tid >= 320 && tid < 324) aux[72 + tid] = 1.f - logsigf(iv[b*ET + 256 + (tid - 320)]);
    __syncthreads();
    if (tid < 4){
        float ss = 0.f;
        #pragma unroll
        for (int w = 0; w < 64; ++w){ float v = aux[128 + w*4 + tid]; ss += v*v; }
        aux[384 + tid] = sqrtf(ss) + 1e-8f;
    }
    __syncthreads();
    if (tid < 256) aux[128 + tid] = aux[128 + tid] / aux[384 + (tid & 3)];
    __syncthreads();

    // ---- M update + read scores (scores -> LDS) ----
    float* Mrow = M + ((size_t)b*1024 + n)*64;
    float dr0=0.f, dr1=0.f, dr2=0.f, dr3=0.f, msq2=0.f;
    #pragma unroll
    for (int w = 0; w < 64; w += 4){
        float4 mv = *(const float4*)(Mrow + w);
        mv.x = mv.x*(1.f - wwv*aux[w+0]) + wwv*aux[64+w+0];
        mv.y = mv.y*(1.f - wwv*aux[w+1]) + wwv*aux[64+w+1];
        mv.z = mv.z*(1.f - wwv*aux[w+2]) + wwv*aux[64+w+2];
        mv.w = mv.w*(1.f - wwv*aux[w+3]) + wwv*aux[64+w+3];
        *(float4*)(Mrow + w) = mv;
        msq2 += mv.x*mv.x + mv.y*mv.y + mv.z*mv.z + mv.w*mv.w;
        dr0 += mv.x*aux[128+(w+0)*4+0] + mv.y*aux[128+(w+1)*4+0] + mv.z*aux[128+(w+2)*4+0] + mv.w*aux[128+(w+3)*4+0];
        dr1 += mv.x*aux[128+(w+0)*4+1] + mv.y*aux[128+(w+1)*4+1] + mv.z*aux[128+(w+2)*4+1] + mv.w*aux[128+(w+3)*4+1];
        dr2 += mv.x*aux[128+(w+0)*4+2] + mv.y*aux[128+(w+1)*4+2] + mv.z*aux[128+(w+2)*4+2] + mv.w*aux[128+(w+3)*4+2];
        dr3 += mv.x*aux[128+(w+0)*4+3] + mv.y*aux[128+(w+1)*4+3] + mv.z*aux[128+(w+2)*4+3] + mv.w*aux[128+(w+3)*4+3];
    }
    float den = sqrtf(msq2) + 1e-8f;
    pS[0*1024 + n] = aux[392]*dr0/den;
    pS[1*1024 + n] = aux[393]*dr1/den;
    pS[2*1024 + n] = aux[394]*dr2/den;
    pS[3*1024 + n] = aux[395]*dr3/den;
    __syncthreads();

    // ---- read softmax per r (r_ = tid>>8 owns 4 n) ----
    const int r_ = tid >> 8, i4 = (tid & 255)*4;
    float v0 = pS[r_*1024 + i4+0], v1 = pS[r_*1024 + i4+1];
    float v2 = pS[r_*1024 + i4+2], v3 = pS[r_*1024 + i4+3];
    float lm = fmaxf(fmaxf(v0,v1), fmaxf(v2,v3));
    #pragma unroll
    for (int off = 32; off > 0; off >>= 1) lm = fmaxf(lm, __shfl_xor(lm, off));
    if (lane == 0) red[wid] = lm;
    __syncthreads();
    if (tid < 4) red[16+tid] = fmaxf(fmaxf(red[4*tid],red[4*tid+1]), fmaxf(red[4*tid+2],red[4*tid+3]));
    __syncthreads();
    float mxr = red[16 + r_];
    float lsum = expf(v0-mxr) + expf(v1-mxr) + expf(v2-mxr) + expf(v3-mxr);
    #pragma unroll
    for (int off = 32; off > 0; off >>= 1) lsum += __shfl_xor(lsum, off);
    if (lane == 0) red[wid] = lsum;
    __syncthreads();
    if (tid < 4) red[20+tid] = red[4*tid]+red[4*tid+1]+red[4*tid+2]+red[4*tid+3];
    __syncthreads();
    float totr = red[20 + r_];
    {
        float w0 = expf(v0-mxr)/totr, w1 = expf(v1-mxr)/totr;
        float w2 = expf(v2-mxr)/totr, w3 = expf(v3-mxr)/totr;
        pS[r_*1024 + i4+0] = w0; pS[r_*1024 + i4+1] = w1;
        pS[r_*1024 + i4+2] = w2; pS[r_*1024 + i4+3] = w3;
        lrw[((size_t)(b*1024 + i4+0))*4 + r_] = w0;
        lrw[((size_t)(b*1024 + i4+1))*4 + r_] = w1;
        lrw[((size_t)(b*1024 + i4+2))*4 + r_] = w2;
        lrw[((size_t)(b*1024 + i4+3))*4 + r_] = w3;
    }
    __syncthreads();

    // ---- read vectors: thread (q = tid>>8, r = (tid>>6)&3, w = tid&63) ----
    {
        const int q = tid >> 8, r = (tid >> 6) & 3, w = tid & 63;
        const float* Mb = M + ((size_t)b*1024 + q*256)*64;
        const float* rb = pS + r*1024 + q*256;
        float acc = 0.f;
        for (int i = 0; i < 256; ++i)
            acc += Mb[(size_t)i*64 + w] * rb[i];
        rvS[tid] = acc;
    }
    __syncthreads();
    if (tid < 256){
        int w2 = tid >> 2, r2 = tid & 3;
        float ssum = 0.f;
        #pragma unroll
        for (int q = 0; q < 4; ++q) ssum += rvS[q*256 + r2*64 + w2];
        lrv[b*256 + tid] = ssum;     // layout [b][w*4+r]
    }
}

// ---------------- final: yt = lrv@Wr + sum(vtp); out = max over t --------------------
// grid (16 m-chunks, 4 b-groups) x 256 thr. thread: 4 m x 1 b.
__global__ void dnc_yfin(const float* __restrict__ lrv, const float* __restrict__ Wr,
                         const float* __restrict__ vtp, float* __restrict__ out, int t){
    const int tid = threadIdx.x;
    const int mg = tid & 31, bgl = tid >> 5;       // bgl 0..7
    const int m0 = blockIdx.x*128 + mg*4;
    const int b  = blockIdx.y*8 + bgl;
    __shared__ float lt[256*9];                    // lrv^T [k][bgl], pad 9
    #pragma unroll
    for (int i = 0; i < 8; ++i)
        lt[tid*9 + i] = lrv[((size_t)(blockIdx.y*8 + i))*256 + tid];
    __syncthreads();
    float4 acc = make_float4(0.f,0.f,0.f,0.f);
    for (int kk = 0; kk < 256; ++kk){
        float av = lt[kk*9 + bgl];
        float4 wv = *(const float4*)&Wr[(size_t)kk*VT + m0];
        acc.x += av*wv.x; acc.y += av*wv.y; acc.z += av*wv.z; acc.w += av*wv.w;
    }
    #pragma unroll
    for (int sp = 0; sp < VKS; ++sp){
        float4 vp = *(const float4*)&vtp[((size_t)sp*BSZ + b)*VT + m0];
        acc.x += vp.x; acc.y += vp.y; acc.z += vp.z; acc.w += vp.w;
    }
    float4* op = (float4*)&out[(size_t)b*VT + m0];
    if (t == 0){ *op = acc; }
    else {
        float4 cur = *op;
        cur.x = fmaxf(cur.x, acc.x); cur.y = fmaxf(cur.y, acc.y);
        cur.z = fmaxf(cur.z, acc.z); cur.w = fmaxf(cur.w, acc.w);
        *op = cur;
    }
}

extern "C" void kernel_launch(void* const* d_in, const int* in_sizes, int n_in,
                              void* d_out, int out_size, void* d_ws, size_t ws_size,
                              hipStream_t stream){
    const float* x      = (const float*)d_in[0];
    const float* mem0   = (const float*)d_in[1];
    const float* Wy     = (const float*)d_in[2];
    const float* WE     = (const float*)d_in[3];
    const float* Wr     = (const float*)d_in[4];
    const float* Wih0   = (const float*)d_in[5];
    const float* Whh0   = (const float*)d_in[6];
    const float* bih0   = (const float*)d_in[7];
    const float* bhh0   = (const float*)d_in[8];
    const float* Wih1   = (const float*)d_in[9];
    const float* Whh1   = (const float*)d_in[10];
    const float* bih1   = (const float*)d_in[11];
    const float* bhh1   = (const float*)d_in[12];
    float* out = (float*)d_out;

    float* p = (float*)d_ws;
    float* M       = p; p += (size_t)BSZ*1024*64;
    float* hstate0 = p; p += 4*BSZ*HD;     // zero block start
    float* hstate1 = p; p += 4*BSZ*HD;
    float* cstate  = p; p += 4*BSZ*HD;
    float* ubuf    = p; p += BSZ*1024;
    float* lww     = p; p += BSZ*1024;
    float* lrw     = p; p += BSZ*1024*4;
    float* lrv     = p; p += BSZ*256;      // zero block end
    float* bnx     = p; p += (size_t)TT*BSZ*XD;
    float* lin1    = p; p += BSZ*1024;
    float* flat    = p; p += BSZ*2048;
    float* vtp     = p; p += (size_t)VKS*BSZ*VT;
    float* ep      = p; p += (size_t)VKS*BSZ*ET;
    float* iv      = p; p += BSZ*ET;
    float* allocw  = p; p += BSZ*1024;
    float* scw     = p; p += BSZ*1024;

    (void)hipMemcpyAsync(M, mem0, (size_t)BSZ*1024*64*sizeof(float), hipMemcpyDeviceToDevice, stream);
    size_t zfloats = (size_t)(4*BSZ*HD)*3 + BSZ*1024*2 + BSZ*1024*4 + BSZ*256;
    (void)hipMemsetAsync(hstate0, 0, zfloats*sizeof(float), stream);

    dnc_bnx<<<TT, 128, 0, stream>>>(x, bnx);

    for (int t = 0; t < TT; ++t){
        const float* hr = (t & 1) ? hstate1 : hstate0;
        float*       hw = (t & 1) ? hstate0 : hstate1;
        dnc_lstm_fused<<<dim3(64,2), 256, 0, stream>>>(bnx + (size_t)t*BSZ*XD, XD,
            lrv, 256, hr, Wih0, Whh0, bih0, bhh0, cstate, hw, flat, lin1, 0);
        dnc_lstm_fused<<<dim3(64,2), 256, 0, stream>>>(lin1, 1024,
            nullptr, 0, hr + 2*BSZ*HD, Wih1, Whh1, bih1, bhh1, cstate, hw, flat, nullptr, 1);
        dnc_gemv2<<<dim3(20,VKS), 256, 0, stream>>>(flat, Wy, WE, vtp, ep);
        dnc_presort_cw<<<64, 1024, 0, stream>>>(ep, lrw, lww, ubuf, iv, allocw, M, scw);
        dnc_memup_rv<<<32, 1024, 0, stream>>>(M, scw, allocw, iv, lww, lrw, lrv);
        dnc_yfin<<<dim3(16,4), 256, 0, stream>>>(lrv, Wr, vtp, out, t);
    }
}